// Round 20
// baseline (16.678 us; speedup 1.0000x reference)
//
#include <hip/hip_runtime.h>
#include <hip/hip_bf16.h>

// S=128, Q=8192, H=230
//   logits[s,q] = a[s] + c[q] + b - 2*sum_k (w*x)[s,k]*y[q,k]
// r19 champion (13.75us) + two cuts:
//   (1) A-build w-loads as float4 (w+kof is 32B-aligned) - halves w VMEM ops
//   (2) cq-reduce (tid<32) overlapped with the MFMA loop; barrier moved
//       to after MFMA (epilogue is the only cq consumer)
// Loss: per-block partial + tiny deterministic reduce kernel.

#define S_DIM 128
#define Q_DIM 8192
#define H_DIM 230
#define K2    256              // bf16 K padded to multiple of 32
#define SQ    (S_DIM * Q_DIM)
#define QB    32               // q-tile per block
#define NBLK  (Q_DIM / QB)     // 256 main blocks

using short8 = __attribute__((ext_vector_type(8))) short;   // 8 bf16 (4 VGPRs)
using f32x4  = __attribute__((ext_vector_type(4))) float;

__device__ __forceinline__ float bf16_to_f32(short bits) {
    unsigned u = ((unsigned)(unsigned short)bits) << 16;
    return __uint_as_float(u);
}
__device__ __forceinline__ unsigned short bf16bits(float f) {
    __hip_bfloat16 h = __float2bfloat16(f);
    return *reinterpret_cast<unsigned short*>(&h);
}
__device__ __forceinline__ unsigned packbf2(float lo, float hi) {
    return (unsigned)bf16bits(lo) | ((unsigned)bf16bits(hi) << 16);
}

// ---------------- Kernel 1: main (MFMA GEMM + sigmoid + BCE) ----------------
// grid=256, block=512 (8 waves). Block: all 128 s x 32 q.
// Wave wid: s in [16*wid, 16*wid+16), q-halves [q0,q0+16) and [q0+16,q0+32).
__global__ __launch_bounds__(512, 2) void main_kernel(
    const float* __restrict__ x, const float* __restrict__ y,
    const int* __restrict__ label, const float* __restrict__ w,
    const float* __restrict__ bptr, float* __restrict__ out,
    float* __restrict__ lossws)
{
    __shared__ __align__(16) short ylb[QB * K2];   // 16 KB bf16, XOR-swizzled
    __shared__ float wl[K2];                       // w zero-padded, f32
    __shared__ float cpart[16][33];
    __shared__ float cq[QB];
    __shared__ float asl[S_DIM];
    __shared__ float lred[8];

    const int tid = threadIdx.x;
    const int q0 = blockIdx.x * QB;
    const int wid = tid >> 6, l = tid & 63;
    const int lm = l & 15, lh = l >> 4;
    const int s_base = wid * 16;
    char* ylc = reinterpret_cast<char*>(ylb);

    // ---- w -> LDS (zero-padded; consumed post-barrier in c[q]) ----
    if (tid < K2) wl[tid] = (tid < H_DIM) ? w[tid] : 0.0f;

    // ---- stage y tile (32 rows x 230 f32) -> bf16 swizzled LDS ----
    const float4* ysrc4 = reinterpret_cast<const float4*>(y + (size_t)q0 * H_DIM);
    #pragma unroll
    for (int it = 0; it < 4; ++it) {
        int i4 = tid + 512 * it;
        if (i4 < (QB * H_DIM) / 4) {
            float4 v = ysrc4[i4];
            int e0 = i4 * 4;
            int r0 = e0 / H_DIM;               // const divide -> magic mul
            int c0 = e0 - r0 * H_DIM;          // even
            int e2 = e0 + 2;
            int r2 = e2 / H_DIM;
            int c2 = e2 - r2 * H_DIM;          // even
            int byt0 = ((r0 << 9) + (c0 << 1)) ^ ((r0 & 7) << 4);
            int byt2 = ((r2 << 9) + (c2 << 1)) ^ ((r2 & 7) << 4);
            *reinterpret_cast<unsigned*>(ylc + byt0) = packbf2(v.x, v.y);
            *reinterpret_cast<unsigned*>(ylc + byt2) = packbf2(v.z, v.w);
        }
    }
    if (tid < QB * (K2 - H_DIM) / 2) {   // zero-fill k=230..255: 32 rows x 13 pairs
        int r = tid & 31, c = H_DIM + 2 * (tid >> 5);
        int byt = ((r << 9) + (c << 1)) ^ ((r & 7) << 4);
        *reinterpret_cast<unsigned*>(ylc + byt) = 0u;
    }

    // ---- label prefetch: issue AFTER staging reads, consume in epilogue ----
    int labs[2][4];
    {
        const size_t ob = (size_t)(s_base + lh * 4) * Q_DIM + q0 + lm;
        #pragma unroll
        for (int r = 0; r < 4; ++r) {
            labs[0][r] = label[ob + (size_t)r * Q_DIM];
            labs[1][r] = label[ob + (size_t)r * Q_DIM + 16];
        }
    }

    // ---- A-frags + a[s] in registers (pre-barrier; overlaps y staging) ----
    // Lane's A row = s_base+lm; k = ks*32 + lh*8 + 2j. ks<=6: unguarded
    // (k <= 222). x as float2 (rows 8B-aligned); w as float4 (kof mult of 8
    // -> 32B-aligned). ks=7: lh==0 pairs 224/226/228 valid; lh>=1 zero.
    short8 afr[8];
    {
        float ap = 0.f;
        const float* xrow = x + (size_t)(s_base + lm) * H_DIM;
        #pragma unroll
        for (int ks = 0; ks < 7; ++ks) {
            const int kof = ks * 32 + lh * 8;
            float4 wA = *reinterpret_cast<const float4*>(w + kof);
            float4 wB = *reinterpret_cast<const float4*>(w + kof + 4);
            const float wv[8] = {wA.x, wA.y, wA.z, wA.w, wB.x, wB.y, wB.z, wB.w};
            short8 a;
            #pragma unroll
            for (int j = 0; j < 4; ++j) {
                int k = kof + 2 * j;
                float2 x2 = *reinterpret_cast<const float2*>(xrow + k);
                float p0 = wv[2 * j] * x2.x, p1 = wv[2 * j + 1] * x2.y;
                a[2 * j]     = (short)bf16bits(p0);
                a[2 * j + 1] = (short)bf16bits(p1);
                ap = fmaf(p1, x2.y, fmaf(p0, x2.x, ap));   // w*x^2 (f32)
            }
            afr[ks] = a;
        }
        {   // ks = 7 boundary tile
            short8 a = {0, 0, 0, 0, 0, 0, 0, 0};
            if (lh == 0) {
                #pragma unroll
                for (int j = 0; j < 3; ++j) {
                    int k = 224 + 2 * j;
                    float2 x2 = *reinterpret_cast<const float2*>(xrow + k);
                    float2 w2 = *reinterpret_cast<const float2*>(w + k);
                    float p0 = w2.x * x2.x, p1 = w2.y * x2.y;
                    a[2 * j]     = (short)bf16bits(p0);
                    a[2 * j + 1] = (short)bf16bits(p1);
                    ap = fmaf(p1, x2.y, fmaf(p0, x2.x, ap));
                }
            }
            afr[7] = a;
        }
        ap += __shfl_xor(ap, 16, 64);
        ap += __shfl_xor(ap, 32, 64);
        if (lh == 0) asl[s_base + lm] = ap;
    }

    __syncthreads();   // bar1: ylb + wl ready

    // ---- c[q] partials: r=tid&31 (q-row), ch=tid>>5 (16 k each) ----
    {
        const int r = tid & 31, ch = tid >> 5;     // ch in 0..15
        const int k0 = ch * 16;
        int byt0 = ((r << 9) + (k0 << 1)) ^ ((r & 7) << 4);
        int byt1 = ((r << 9) + ((k0 + 8) << 1)) ^ ((r & 7) << 4);
        short8 v8a = *reinterpret_cast<const short8*>(ylc + byt0);
        short8 v8b = *reinterpret_cast<const short8*>(ylc + byt1);
        float p = 0.f;
        #pragma unroll
        for (int j = 0; j < 8; ++j) {
            float va = bf16_to_f32(v8a[j]);
            p = fmaf(wl[k0 + j] * va, va, p);
        }
        #pragma unroll
        for (int j = 0; j < 8; ++j) {
            float vb = bf16_to_f32(v8b[j]);
            p = fmaf(wl[k0 + 8 + j] * vb, vb, p);
        }
        cpart[ch][r] = p;
    }
    __syncthreads();   // bar2: cpart ready

    // ---- cq reduce (tid<32) overlapped with MFMA below ----
    if (tid < QB) {
        float c = 0.f;
        #pragma unroll
        for (int ch = 0; ch < 16; ++ch) c += cpart[ch][tid];
        cq[tid] = c + bptr[0];                     // fold bias in
    }

    // ---- MFMA k-loop: wave computes 16 s x 32 q (2 accs, A from registers) ----
    f32x4 acc0 = {0.f, 0.f, 0.f, 0.f};
    f32x4 acc1 = {0.f, 0.f, 0.f, 0.f};
    #pragma unroll
    for (int ks = 0; ks < K2 / 32; ++ks) {
        const int kof = ks * 32 + lh * 8;
        int byt0 = ((lm << 9) + (kof << 1)) ^ ((lm & 7) << 4);
        int byt1 = (((lm + 16) << 9) + (kof << 1)) ^ ((lm & 7) << 4);
        short8 bf0 = *reinterpret_cast<const short8*>(ylc + byt0);
        short8 bf1 = *reinterpret_cast<const short8*>(ylc + byt1);
        acc0 = __builtin_amdgcn_mfma_f32_16x16x32_bf16(afr[ks], bf0, acc0, 0, 0, 0);
        acc1 = __builtin_amdgcn_mfma_f32_16x16x32_bf16(afr[ks], bf1, acc1, 0, 0, 0);
    }
    __syncthreads();   // bar3: cq ready

    // ---- epilogue (branch-free, 2 transcendentals/element) ----
    // em = e^-|z| in (0,1]; t = rcp(1+em); sigmoid = z>=0 ? t : em*t.
    // bce = z*(1-lab) + max(-z,0) + log(1+e^-|z|), log terms folded as
    // ONE v_log per thread: lsum += ln2 * log2(prod(1+em)), prod <= 256.
    float asum_l = 0.f, prod = 1.f;
    const float cq0 = cq[lm], cq1 = cq[lm + 16];
    #pragma unroll
    for (int r = 0; r < 4; ++r) {
        int s = s_base + lh * 4 + r;               // D row=(l>>4)*4+r, col=l&15
        size_t o = (size_t)s * Q_DIM + q0 + lm;
        float az = asl[s];
        {
            float z = az + cq0 - 2.0f * acc0[r];
            float em = __expf(-fabsf(z));
            float opem = 1.0f + em;
            float t = __builtin_amdgcn_rcpf(opem);
            out[o] = (z >= 0.0f) ? t : em * t;
            float lab = (float)labs[0][r];
            asum_l += z * (1.0f - lab) + fmaxf(-z, 0.0f);
            prod *= opem;
        }
        {
            float z = az + cq1 - 2.0f * acc1[r];
            float em = __expf(-fabsf(z));
            float opem = 1.0f + em;
            float t = __builtin_amdgcn_rcpf(opem);
            out[o + 16] = (z >= 0.0f) ? t : em * t;
            float lab = (float)labs[1][r];
            asum_l += z * (1.0f - lab) + fmaxf(-z, 0.0f);
            prod *= opem;
        }
    }
    float lsum = asum_l + 0.69314718055994531f * __log2f(prod);
    #pragma unroll
    for (int off = 32; off >= 1; off >>= 1) lsum += __shfl_down(lsum, off, 64);
    if (l == 0) lred[wid] = lsum;
    __syncthreads();
    if (tid == 0) {
        float blk = 0.f;
        #pragma unroll
        for (int i = 0; i < 8; ++i) blk += lred[i];
        lossws[blockIdx.x] = blk;
    }
}

// ---------------- Kernel 2: deterministic loss reduce ----------------
__global__ __launch_bounds__(256) void loss_reduce_kernel(
    const float* __restrict__ lossws, float* __restrict__ out)
{
    __shared__ float lred[4];
    const int tid = threadIdx.x;
    float p = lossws[tid];                         // NBLK=256 partials
    #pragma unroll
    for (int off = 32; off >= 1; off >>= 1) p += __shfl_down(p, off, 64);
    if ((tid & 63) == 0) lred[tid >> 6] = p;
    __syncthreads();
    if (tid == 0)
        out[SQ] = (lred[0] + lred[1] + lred[2] + lred[3]) * (1.0f / (float)SQ);
}

extern "C" void kernel_launch(void* const* d_in, const int* in_sizes, int n_in,
                              void* d_out, int out_size, void* d_ws, size_t ws_size,
                              hipStream_t stream) {
    const float* x = (const float*)d_in[0];     // [128,230]
    const float* y = (const float*)d_in[1];     // [8192,230]
    const int* label = (const int*)d_in[2];     // [128,8192]
    const float* w = (const float*)d_in[3];     // [230]
    const float* b = (const float*)d_in[4];     // [1]
    float* out = (float*)d_out;                 // [128*8192 + 1]

    float* lossws = (float*)d_ws;               // [256]

    main_kernel<<<NBLK, 512, 0, stream>>>(x, y, label, w, b, out, lossws);
    loss_reduce_kernel<<<1, 256, 0, stream>>>(lossws, out);
}

// Round 21
// 13.546 us; speedup vs baseline: 1.2312x; 1.2312x over previous
//
#include <hip/hip_runtime.h>
#include <hip/hip_bf16.h>

// S=128, Q=8192, H=230
//   logits[s,q] = a[s] + c[q] + b - 2*sum_k (w*x)[s,k]*y[q,k]
// CHAMPION (r19, 13.75us): single fused main (no prep) + tiny loss reduce.
//   - per-wave A-frags bf16(w*x) built in regs pre-barrier (unguarded ks<=6,
//     special-cased ks=7 boundary), a[s] via shfl_xor byproduct
//   - y-tile -> XOR-swizzled bf16 LDS via packed ds_write_b32
//   - label prefetch after staging reads (in flight across barriers)
//   - barrier BEFORE MFMA (waves destagger into the epilogue - r20 lesson)
//   - branch-free epilogue: em=exp(-|z|), rcp sigmoid, product-log BCE
// All reductions fixed-order (graph replay bitwise identical).

#define S_DIM 128
#define Q_DIM 8192
#define H_DIM 230
#define K2    256              // bf16 K padded to multiple of 32
#define SQ    (S_DIM * Q_DIM)
#define QB    32               // q-tile per block
#define NBLK  (Q_DIM / QB)     // 256 main blocks

using short8 = __attribute__((ext_vector_type(8))) short;   // 8 bf16 (4 VGPRs)
using f32x4  = __attribute__((ext_vector_type(4))) float;

__device__ __forceinline__ float bf16_to_f32(short bits) {
    unsigned u = ((unsigned)(unsigned short)bits) << 16;
    return __uint_as_float(u);
}
__device__ __forceinline__ unsigned short bf16bits(float f) {
    __hip_bfloat16 h = __float2bfloat16(f);
    return *reinterpret_cast<unsigned short*>(&h);
}
__device__ __forceinline__ unsigned packbf2(float lo, float hi) {
    return (unsigned)bf16bits(lo) | ((unsigned)bf16bits(hi) << 16);
}

// ---------------- Kernel 1: main (MFMA GEMM + sigmoid + BCE) ----------------
// grid=256, block=512 (8 waves). Block: all 128 s x 32 q.
// Wave wid: s in [16*wid, 16*wid+16), q-halves [q0,q0+16) and [q0+16,q0+32).
__global__ __launch_bounds__(512, 2) void main_kernel(
    const float* __restrict__ x, const float* __restrict__ y,
    const int* __restrict__ label, const float* __restrict__ w,
    const float* __restrict__ bptr, float* __restrict__ out,
    float* __restrict__ lossws)
{
    __shared__ __align__(16) short ylb[QB * K2];   // 16 KB bf16, XOR-swizzled
    __shared__ float wl[K2];                       // w zero-padded, f32
    __shared__ float cpart[16][33];
    __shared__ float cq[QB];
    __shared__ float asl[S_DIM];
    __shared__ float lred[8];

    const int tid = threadIdx.x;
    const int q0 = blockIdx.x * QB;
    const int wid = tid >> 6, l = tid & 63;
    const int lm = l & 15, lh = l >> 4;
    const int s_base = wid * 16;
    char* ylc = reinterpret_cast<char*>(ylb);

    // ---- w -> LDS (zero-padded; consumed post-barrier in c[q]) ----
    if (tid < K2) wl[tid] = (tid < H_DIM) ? w[tid] : 0.0f;

    // ---- stage y tile (32 rows x 230 f32) -> bf16 swizzled LDS ----
    const float4* ysrc4 = reinterpret_cast<const float4*>(y + (size_t)q0 * H_DIM);
    #pragma unroll
    for (int it = 0; it < 4; ++it) {
        int i4 = tid + 512 * it;
        if (i4 < (QB * H_DIM) / 4) {
            float4 v = ysrc4[i4];
            int e0 = i4 * 4;
            int r0 = e0 / H_DIM;               // const divide -> magic mul
            int c0 = e0 - r0 * H_DIM;          // even
            int e2 = e0 + 2;
            int r2 = e2 / H_DIM;
            int c2 = e2 - r2 * H_DIM;          // even
            int byt0 = ((r0 << 9) + (c0 << 1)) ^ ((r0 & 7) << 4);
            int byt2 = ((r2 << 9) + (c2 << 1)) ^ ((r2 & 7) << 4);
            *reinterpret_cast<unsigned*>(ylc + byt0) = packbf2(v.x, v.y);
            *reinterpret_cast<unsigned*>(ylc + byt2) = packbf2(v.z, v.w);
        }
    }
    if (tid < QB * (K2 - H_DIM) / 2) {   // zero-fill k=230..255: 32 rows x 13 pairs
        int r = tid & 31, c = H_DIM + 2 * (tid >> 5);
        int byt = ((r << 9) + (c << 1)) ^ ((r & 7) << 4);
        *reinterpret_cast<unsigned*>(ylc + byt) = 0u;
    }

    // ---- label prefetch: issue AFTER staging reads, consume in epilogue ----
    int labs[2][4];
    {
        const size_t ob = (size_t)(s_base + lh * 4) * Q_DIM + q0 + lm;
        #pragma unroll
        for (int r = 0; r < 4; ++r) {
            labs[0][r] = label[ob + (size_t)r * Q_DIM];
            labs[1][r] = label[ob + (size_t)r * Q_DIM + 16];
        }
    }

    // ---- A-frags + a[s] in registers (pre-barrier; overlaps y staging) ----
    // Lane's A row = s_base+lm; k = ks*32 + lh*8 + 2j. ks<=6: unguarded
    // (k <= 222 < 230), float2 8B-aligned (rows start at even f32 offsets).
    // ks=7: lh==0 pairs 224/226/228 valid; lh>=1 all zero.
    short8 afr[8];
    {
        float ap = 0.f;
        const float* xrow = x + (size_t)(s_base + lm) * H_DIM;
        #pragma unroll
        for (int ks = 0; ks < 7; ++ks) {
            const int kof = ks * 32 + lh * 8;
            short8 a;
            #pragma unroll
            for (int j = 0; j < 4; ++j) {
                int k = kof + 2 * j;
                float2 x2 = *reinterpret_cast<const float2*>(xrow + k);
                float2 w2 = *reinterpret_cast<const float2*>(w + k);
                float p0 = w2.x * x2.x, p1 = w2.y * x2.y;
                a[2 * j]     = (short)bf16bits(p0);
                a[2 * j + 1] = (short)bf16bits(p1);
                ap = fmaf(p1, x2.y, fmaf(p0, x2.x, ap));   // w*x^2 (f32)
            }
            afr[ks] = a;
        }
        {   // ks = 7 boundary tile
            short8 a = {0, 0, 0, 0, 0, 0, 0, 0};
            if (lh == 0) {
                #pragma unroll
                for (int j = 0; j < 3; ++j) {
                    int k = 224 + 2 * j;
                    float2 x2 = *reinterpret_cast<const float2*>(xrow + k);
                    float2 w2 = *reinterpret_cast<const float2*>(w + k);
                    float p0 = w2.x * x2.x, p1 = w2.y * x2.y;
                    a[2 * j]     = (short)bf16bits(p0);
                    a[2 * j + 1] = (short)bf16bits(p1);
                    ap = fmaf(p1, x2.y, fmaf(p0, x2.x, ap));
                }
            }
            afr[7] = a;
        }
        ap += __shfl_xor(ap, 16, 64);
        ap += __shfl_xor(ap, 32, 64);
        if (lh == 0) asl[s_base + lm] = ap;
    }

    __syncthreads();   // bar1: ylb + wl ready

    // ---- c[q] partials: r=tid&31 (q-row), ch=tid>>5 (16 k each) ----
    {
        const int r = tid & 31, ch = tid >> 5;     // ch in 0..15
        const int k0 = ch * 16;
        int byt0 = ((r << 9) + (k0 << 1)) ^ ((r & 7) << 4);
        int byt1 = ((r << 9) + ((k0 + 8) << 1)) ^ ((r & 7) << 4);
        short8 v8a = *reinterpret_cast<const short8*>(ylc + byt0);
        short8 v8b = *reinterpret_cast<const short8*>(ylc + byt1);
        float p = 0.f;
        #pragma unroll
        for (int j = 0; j < 8; ++j) {
            float va = bf16_to_f32(v8a[j]);
            p = fmaf(wl[k0 + j] * va, va, p);
        }
        #pragma unroll
        for (int j = 0; j < 8; ++j) {
            float vb = bf16_to_f32(v8b[j]);
            p = fmaf(wl[k0 + 8 + j] * vb, vb, p);
        }
        cpart[ch][r] = p;
    }
    __syncthreads();   // bar2: cpart ready
    if (tid < QB) {
        float c = 0.f;
        #pragma unroll
        for (int ch = 0; ch < 16; ++ch) c += cpart[ch][tid];
        cq[tid] = c + bptr[0];                     // fold bias in
    }
    __syncthreads();   // bar3 BEFORE MFMA: waves destagger into epilogue

    // ---- MFMA k-loop: wave computes 16 s x 32 q (2 accs, A from registers) ----
    f32x4 acc0 = {0.f, 0.f, 0.f, 0.f};
    f32x4 acc1 = {0.f, 0.f, 0.f, 0.f};
    #pragma unroll
    for (int ks = 0; ks < K2 / 32; ++ks) {
        const int kof = ks * 32 + lh * 8;
        int byt0 = ((lm << 9) + (kof << 1)) ^ ((lm & 7) << 4);
        int byt1 = (((lm + 16) << 9) + (kof << 1)) ^ ((lm & 7) << 4);
        short8 bf0 = *reinterpret_cast<const short8*>(ylc + byt0);
        short8 bf1 = *reinterpret_cast<const short8*>(ylc + byt1);
        acc0 = __builtin_amdgcn_mfma_f32_16x16x32_bf16(afr[ks], bf0, acc0, 0, 0, 0);
        acc1 = __builtin_amdgcn_mfma_f32_16x16x32_bf16(afr[ks], bf1, acc1, 0, 0, 0);
    }

    // ---- epilogue (branch-free, 2 transcendentals/element) ----
    // em = e^-|z| in (0,1]; t = rcp(1+em); sigmoid = z>=0 ? t : em*t.
    // bce = z*(1-lab) + max(-z,0) + log(1+e^-|z|), log terms folded as
    // ONE v_log per thread: lsum += ln2 * log2(prod(1+em)), prod <= 256.
    float asum_l = 0.f, prod = 1.f;
    const float cq0 = cq[lm], cq1 = cq[lm + 16];
    #pragma unroll
    for (int r = 0; r < 4; ++r) {
        int s = s_base + lh * 4 + r;               // D row=(l>>4)*4+r, col=l&15
        size_t o = (size_t)s * Q_DIM + q0 + lm;
        float az = asl[s];
        {
            float z = az + cq0 - 2.0f * acc0[r];
            float em = __expf(-fabsf(z));
            float opem = 1.0f + em;
            float t = __builtin_amdgcn_rcpf(opem);
            out[o] = (z >= 0.0f) ? t : em * t;
            float lab = (float)labs[0][r];
            asum_l += z * (1.0f - lab) + fmaxf(-z, 0.0f);
            prod *= opem;
        }
        {
            float z = az + cq1 - 2.0f * acc1[r];
            float em = __expf(-fabsf(z));
            float opem = 1.0f + em;
            float t = __builtin_amdgcn_rcpf(opem);
            out[o + 16] = (z >= 0.0f) ? t : em * t;
            float lab = (float)labs[1][r];
            asum_l += z * (1.0f - lab) + fmaxf(-z, 0.0f);
            prod *= opem;
        }
    }
    float lsum = asum_l + 0.69314718055994531f * __log2f(prod);
    #pragma unroll
    for (int off = 32; off >= 1; off >>= 1) lsum += __shfl_down(lsum, off, 64);
    if (l == 0) lred[wid] = lsum;
    __syncthreads();
    if (tid == 0) {
        float blk = 0.f;
        #pragma unroll
        for (int i = 0; i < 8; ++i) blk += lred[i];
        lossws[blockIdx.x] = blk;
    }
}

// ---------------- Kernel 2: deterministic loss reduce ----------------
__global__ __launch_bounds__(256) void loss_reduce_kernel(
    const float* __restrict__ lossws, float* __restrict__ out)
{
    __shared__ float lred[4];
    const int tid = threadIdx.x;
    float p = lossws[tid];                         // NBLK=256 partials
    #pragma unroll
    for (int off = 32; off >= 1; off >>= 1) p += __shfl_down(p, off, 64);
    if ((tid & 63) == 0) lred[tid >> 6] = p;
    __syncthreads();
    if (tid == 0)
        out[SQ] = (lred[0] + lred[1] + lred[2] + lred[3]) * (1.0f / (float)SQ);
}

extern "C" void kernel_launch(void* const* d_in, const int* in_sizes, int n_in,
                              void* d_out, int out_size, void* d_ws, size_t ws_size,
                              hipStream_t stream) {
    const float* x = (const float*)d_in[0];     // [128,230]
    const float* y = (const float*)d_in[1];     // [8192,230]
    const int* label = (const int*)d_in[2];     // [128,8192]
    const float* w = (const float*)d_in[3];     // [230]
    const float* b = (const float*)d_in[4];     // [1]
    float* out = (float*)d_out;                 // [128*8192 + 1]

    float* lossws = (float*)d_ws;               // [256]

    main_kernel<<<NBLK, 512, 0, stream>>>(x, y, label, w, b, out, lossws);
    loss_reduce_kernel<<<1, 256, 0, stream>>>(lossws, out);
}